// Round 5
// baseline (651.299 us; speedup 1.0000x reference)
//
#include <hip/hip_runtime.h>
#include <hip/hip_bf16.h>

// Problem constants (fixed by the reference file).
constexpr int N_NODES = 20000;
constexpr int N_EDGES = 640000;
constexpr int D = 128;          // D_IN == D_OUT == 128
constexpr int N_TILES_NODE = (N_NODES + 63) / 64;   // 313
constexpr int N_TILES_EDGE = N_EDGES / 128;         // 5000
constexpr int SCAT_BLOCKS  = (N_EDGES + 255) / 256; // 2500
constexpr int TLD = 129;        // block tile leading dim: 128 m + 1 pad

typedef float  f32x4  __attribute__((ext_vector_type(4)));
typedef short  short8 __attribute__((ext_vector_type(8)));

// fp32 -> bf16 bits, round-to-nearest-even (scalar)
__device__ inline short f2bf(float f) {
    unsigned u = __builtin_bit_cast(unsigned, f);
    u += 0x7fffu + ((u >> 16) & 1u);
    return (short)(u >> 16);
}
__device__ inline float bf2f(short s) {
    unsigned u = ((unsigned)(unsigned short)s) << 16;
    return __builtin_bit_cast(float, u);
}
// packed fp32x2 -> bf16x2 (RNE), single HW instruction
__device__ inline unsigned cvt_pk_bf16(float a, float b) {
    unsigned r;
    asm("v_cvt_pk_bf16_f32 %0, %1, %2" : "=v"(r) : "v"(a), "v"(b));
    return r;
}

// ---------------------------------------------------------------------------
// Prep: weight fragments (We -> fragE bf16; Wn -> fragH/fragL hi/lo split)
// + zero the counting-sort histogram (explicit: the harness fill pattern is
// not guaranteed to be zero).
// ---------------------------------------------------------------------------
__global__ __launch_bounds__(256) void prep_kernel(
    const float* __restrict__ We, const float* __restrict__ Wn,
    short8* __restrict__ fragE, short8* __restrict__ fragH,
    short8* __restrict__ fragL, int* __restrict__ count)
{
    const int t = blockIdx.x * 256 + threadIdx.x;   // 2048 threads
    for (int i = t; i < N_NODES; i += 2048) count[i] = 0;

    const int n = t >> 4, k8 = t & 15;
    const int kt = k8 >> 2, q = k8 & 3;
    const int fi = ((n >> 4) * 4 + kt) * 64 + q * 16 + (n & 15);

    {
        const float4 x = *(const float4*)(We + n * D + k8 * 8);
        const float4 y = *(const float4*)(We + n * D + k8 * 8 + 4);
        short8 s;
        unsigned* sp = (unsigned*)&s;
        sp[0] = cvt_pk_bf16(x.x, x.y);
        sp[1] = cvt_pk_bf16(x.z, x.w);
        sp[2] = cvt_pk_bf16(y.x, y.y);
        sp[3] = cvt_pk_bf16(y.z, y.w);
        fragE[fi] = s;
    }
    {
        const float4 x = *(const float4*)(Wn + n * D + k8 * 8);
        const float4 y = *(const float4*)(Wn + n * D + k8 * 8 + 4);
        const float v[8] = {x.x, x.y, x.z, x.w, y.x, y.y, y.z, y.w};
        short8 hi, lo;
        #pragma unroll
        for (int j = 0; j < 8; ++j) {
            hi[j] = f2bf(v[j]);
            lo[j] = f2bf(v[j] - bf2f(hi[j]));
        }
        fragH[fi] = hi;
        fragL[fi] = lo;
    }
}

// ---------------------------------------------------------------------------
// Counting sort: histogram, scan (scatter merged with node below).
// ---------------------------------------------------------------------------
__global__ __launch_bounds__(256) void hist_kernel(
    const int* __restrict__ dst, int* __restrict__ count)
{
    const int e = blockIdx.x * 256 + threadIdx.x;
    if (e < N_EDGES) atomicAdd(&count[dst[e]], 1);
}

__global__ __launch_bounds__(1024) void scan_kernel(
    const int* __restrict__ count, int* __restrict__ cursor)
{
    constexpr int PER = 20;                    // 1024*20 = 20480 >= 20000
    __shared__ int tot[1024];
    const int tid = threadIdx.x;
    const int base = tid * PER;

    int local[PER];
    int s = 0;
    #pragma unroll
    for (int i = 0; i < PER; ++i) {
        const int idx = base + i;
        const int v = (idx < N_NODES) ? count[idx] : 0;
        local[i] = s;
        s += v;
    }
    tot[tid] = s;
    __syncthreads();
    for (int off = 1; off < 1024; off <<= 1) {
        const int add = (tid >= off) ? tot[tid - off] : 0;
        __syncthreads();
        tot[tid] += add;
        __syncthreads();
    }
    const int excl = tot[tid] - s;
    #pragma unroll
    for (int i = 0; i < PER; ++i) {
        const int idx = base + i;
        if (idx < N_NODES) cursor[idx] = excl + local[i];
    }
}

// ---------------------------------------------------------------------------
// Node tile body: h = nf @ Wn.T + bn (hi/lo bf16 split, ~fp32 exact),
// h -> workspace; out = relu(h + res_w) / degs (residual init).
// ---------------------------------------------------------------------------
__device__ __forceinline__ void node_tile(
    int tb, int tid,
    const float* __restrict__ nf, const float* __restrict__ degs,
    const short8* __restrict__ fragH, const short8* __restrict__ fragL,
    const float* __restrict__ bn, const float* __restrict__ res_w,
    float* __restrict__ h_ws, float* __restrict__ out)
{
    const int lane = tid & 63, wave = tid >> 6;
    const int quad = lane >> 4, row16 = lane & 15;
    const int mbase = tb * 64 + wave * 16;

    const int arow = min(mbase + row16, N_NODES - 1);
    short8 ah[4], al[4];
    const float* p = nf + arow * D + quad * 8;
    #pragma unroll
    for (int kt = 0; kt < 4; ++kt) {
        const float4 x = *(const float4*)(p + kt * 32);
        const float4 y = *(const float4*)(p + kt * 32 + 4);
        const float v[8] = {x.x, x.y, x.z, x.w, y.x, y.y, y.z, y.w};
        #pragma unroll
        for (int j = 0; j < 8; ++j) {
            ah[kt][j] = f2bf(v[j]);
            al[kt][j] = f2bf(v[j] - bf2f(ah[kt][j]));
        }
    }

    int   orow[4];
    float dinv[4];
    #pragma unroll
    for (int r = 0; r < 4; ++r) {
        orow[r] = mbase + quad * 4 + r;
        dinv[r] = 1.0f / degs[min(orow[r], N_NODES - 1)];
    }

    #pragma unroll
    for (int nt = 0; nt < 8; ++nt) {
        f32x4 acc = {0.f, 0.f, 0.f, 0.f};
        #pragma unroll
        for (int kt = 0; kt < 4; ++kt) {
            const short8 bh = fragH[(nt * 4 + kt) * 64 + lane];
            const short8 bl = fragL[(nt * 4 + kt) * 64 + lane];
            acc = __builtin_amdgcn_mfma_f32_16x16x32_bf16(al[kt], bh, acc, 0, 0, 0);
            acc = __builtin_amdgcn_mfma_f32_16x16x32_bf16(ah[kt], bl, acc, 0, 0, 0);
            acc = __builtin_amdgcn_mfma_f32_16x16x32_bf16(ah[kt], bh, acc, 0, 0, 0);
        }
        const int col = nt * 16 + row16;
        const float bnv = bn[col], rwv = res_w[col];
        #pragma unroll
        for (int r = 0; r < 4; ++r) {
            if (orow[r] < N_NODES) {
                const float hv = acc[r] + bnv;
                h_ws[orow[r] * D + col] = hv;
                out[orow[r] * D + col] = fmaxf(hv + rwv, 0.0f) * dinv[r];
            }
        }
    }
}

// ---------------------------------------------------------------------------
// Mid kernel: node tiles (blocks [0, N_TILES_NODE)) + scatter (rest).
// Scatter writes ONE 8B int2 (perm,dst) per edge.
// ---------------------------------------------------------------------------
__global__ __launch_bounds__(256) void mid_kernel(
    const int* __restrict__ dst, int* __restrict__ cursor,
    int2* __restrict__ pd,
    const float* __restrict__ nf, const float* __restrict__ degs,
    const short8* __restrict__ fragH, const short8* __restrict__ fragL,
    const float* __restrict__ bn, const float* __restrict__ res_w,
    float* __restrict__ h_ws, float* __restrict__ out)
{
    if (blockIdx.x < N_TILES_NODE) {
        node_tile(blockIdx.x, threadIdx.x, nf, degs, fragH, fragL,
                  bn, res_w, h_ws, out);
    } else {
        const int e = (blockIdx.x - N_TILES_NODE) * 256 + threadIdx.x;
        if (e < N_EDGES) {
            const int d = dst[e];
            const int pos = atomicAdd(&cursor[d], 1);
            pd[pos] = make_int2(e, d);
        }
    }
}

// ---------------------------------------------------------------------------
// Edge kernel: edges in dst-sorted order (pd = packed perm,dst).
//   e   = ef[perm] @ We.T + be   (bf16 MFMA, B-fragments from global fragE)
//   msg = norm * relu(h[src] + e)
//   BLOCK-level segmented sum over sorted-dst runs.
//
// Aggregation (the change this round): per g-phase all 4 waves write their
// 32-edge msg sub-tiles into ONE shared [32 col][128 m] LDS tile; wave 0 then
// scans 64-position windows.  Runs STRICTLY INTERIOR to a window are fully
// contained in this block (dst-sorted => contiguous), and a 64B line of `out`
// belongs to exactly one dst row, so interior runs use plain cached
// load+add+store; only head/tail runs (may span windows/blocks) use
// device-scope atomicAdd.  Cuts atomics ~3x (7.7M -> ~2.6M).
// ---------------------------------------------------------------------------
__global__ __launch_bounds__(256) void edge_kernel(
    const float* __restrict__ ef, const float* __restrict__ norm,
    const int* __restrict__ src, const int2* __restrict__ pd,
    const short8* __restrict__ fragE, const float* __restrict__ be,
    const float* __restrict__ h, float* __restrict__ out)
{
    __shared__ float tile[32 * TLD];   // 16512 B: [col][m], m = block position
    __shared__ int   sdst[128];        // block-wide sorted dst

    const int t = threadIdx.x;
    const int lane  = t & 63;
    const int quad  = lane >> 4;
    const int row16 = lane & 15;
    const int wave  = t >> 6;
    const int p0 = blockIdx.x * 128 + wave * 32;   // 32 sorted positions/wave

    int2 pdv = make_int2(0, 0);
    if (lane < 32) {
        pdv = pd[p0 + lane];
        sdst[wave * 32 + lane] = pdv.y;
    }

    // ---- A fragments: perm via cross-lane shfl, gather edge rows, fp32->bf16
    short8 afr[2][4];
    #pragma unroll
    for (int mt = 0; mt < 2; ++mt) {
        const int erow = __shfl(pdv.x, mt * 16 + row16, 64);
        const float* p = ef + erow * D + quad * 8;
        #pragma unroll
        for (int kt = 0; kt < 4; ++kt) {
            const float4 x = *(const float4*)(p + kt * 32);
            const float4 y = *(const float4*)(p + kt * 32 + 4);
            short8 a;
            unsigned* ap = (unsigned*)&a;
            ap[0] = cvt_pk_bf16(x.x, x.y);
            ap[1] = cvt_pk_bf16(x.z, x.w);
            ap[2] = cvt_pk_bf16(y.x, y.y);
            ap[3] = cvt_pk_bf16(y.z, y.w);
            afr[mt][kt] = a;
        }
    }

    // ---- Edge metadata for the epilogue rows this lane owns
    int   sidx[2][4];
    float nrm[2][4];
    #pragma unroll
    for (int mt = 0; mt < 2; ++mt) {
        #pragma unroll
        for (int r = 0; r < 4; ++r) {
            const int pe = __shfl(pdv.x, mt * 16 + quad * 4 + r, 64);
            sidx[mt][r] = src[pe];
            nrm[mt][r]  = norm[pe];
        }
    }

    __syncthreads();   // sdst visible block-wide

    #pragma unroll
    for (int g = 0; g < 4; ++g) {
        // (1) h prefetch for this group's two 16-col tiles
        float hv[2][2][4];
        #pragma unroll
        for (int t2 = 0; t2 < 2; ++t2)
            #pragma unroll
            for (int mt = 0; mt < 2; ++mt)
                #pragma unroll
                for (int r = 0; r < 4; ++r)
                    hv[t2][mt][r] = h[sidx[mt][r] * D + (g * 2 + t2) * 16 + row16];

        // (2) MFMA both column tiles
        f32x4 acc[2][2];
        #pragma unroll
        for (int t2 = 0; t2 < 2; ++t2) {
            const int nt = g * 2 + t2;
            short8 bfr[4];
            #pragma unroll
            for (int kt = 0; kt < 4; ++kt)
                bfr[kt] = fragE[(nt * 4 + kt) * 64 + lane];
            f32x4 a0 = {0.f, 0.f, 0.f, 0.f};
            f32x4 a1 = {0.f, 0.f, 0.f, 0.f};
            #pragma unroll
            for (int kt = 0; kt < 4; ++kt) {
                a0 = __builtin_amdgcn_mfma_f32_16x16x32_bf16(afr[0][kt], bfr[kt], a0, 0, 0, 0);
                a1 = __builtin_amdgcn_mfma_f32_16x16x32_bf16(afr[1][kt], bfr[kt], a1, 0, 0, 0);
            }
            acc[t2][0] = a0;
            acc[t2][1] = a1;
        }

        // (3) epilogue: msg = norm * relu(h + e + be) -> shared tile[col][m],
        //     m = wave*32 + mt*16 + quad*4 + r  (block position)
        #pragma unroll
        for (int t2 = 0; t2 < 2; ++t2) {
            const int col = (g * 2 + t2) * 16 + row16;
            const float bev = be[col];
            float* tp = tile + (t2 * 16 + row16) * TLD + wave * 32;
            #pragma unroll
            for (int r = 0; r < 4; ++r) {
                const int m0 = quad * 4 + r;
                tp[m0]      = nrm[0][r] * fmaxf(hv[t2][0][r] + acc[t2][0][r] + bev, 0.0f);
                tp[m0 + 16] = nrm[1][r] * fmaxf(hv[t2][1][r] + acc[t2][1][r] + bev, 0.0f);
            }
        }
        __syncthreads();   // tile complete for this g

        // (4) block-level segmented scan, wave 0 only:
        //     lane = col (0..31) + 32*chunk; window = 64 sorted positions.
        //     head/tail runs -> atomicAdd (may span windows/blocks);
        //     interior runs -> plain cached RMW (provably block-private).
        if (wave == 0) {
            const int col  = lane & 31;
            const int mbeg = (lane >> 5) * 64;
            const float* sp = tile + col * TLD;
            const int gcol = g * 32 + col;
            int   cur  = sdst[mbeg];
            float sum  = sp[mbeg];
            bool  head = true;
            #pragma unroll 16
            for (int m = mbeg + 1; m < mbeg + 64; ++m) {
                const int dm = sdst[m];
                const float v = sp[m];
                if (dm != cur) {
                    float* op = &out[cur * D + gcol];
                    if (head) { atomicAdd(op, sum); head = false; }
                    else      { *op += sum; }          // interior run: private
                    sum = 0.0f;
                    cur = dm;
                }
                sum += v;
            }
            atomicAdd(&out[cur * D + gcol], sum);       // tail run
        }
        __syncthreads();   // tile reusable for next g
    }
}

extern "C" void kernel_launch(void* const* d_in, const int* in_sizes, int n_in,
                              void* d_out, int out_size, void* d_ws, size_t ws_size,
                              hipStream_t stream) {
    const float* node_feats = (const float*)d_in[0];
    const float* edge_feats = (const float*)d_in[1];
    const float* degs       = (const float*)d_in[2];
    const float* norm       = (const float*)d_in[3];
    const int*   src        = (const int*)d_in[4];
    const int*   dst        = (const int*)d_in[5];
    const float* Wn         = (const float*)d_in[6];
    const float* bn         = (const float*)d_in[7];
    const float* We         = (const float*)d_in[8];
    const float* be         = (const float*)d_in[9];
    const float* res_w      = (const float*)d_in[10];

    float* out = (float*)d_out;

    // Workspace layout (bytes):
    //   h:      [0,        10240000)   N*D fp32
    //   pd:     [10240000, 15360000)   E int2 (perm, dst) packed
    //   count:  [15360000, 15440000)   N i32 (scan in place; doubles as cursor)
    //   fragE:  [15500000, +32768)     We bf16 fragments
    //   fragH:  [15600000, +32768)     Wn hi fragments
    //   fragL:  [15700000, +32768)     Wn lo fragments
    char* ws = (char*)d_ws;
    float*  h_ws  = (float*)(ws);
    int2*   pd    = (int2*)(ws + 10240000);
    int*    count = (int*)(ws + 15360000);
    short8* fragE = (short8*)(ws + 15500000);
    short8* fragH = (short8*)(ws + 15600000);
    short8* fragL = (short8*)(ws + 15700000);

    // 0) weight fragments + histogram zero
    prep_kernel<<<8, 256, 0, stream>>>(We, Wn, fragE, fragH, fragL, count);

    // 1) histogram + scan
    hist_kernel<<<SCAT_BLOCKS, 256, 0, stream>>>(dst, count);
    scan_kernel<<<1, 1024, 0, stream>>>(count, count);

    // 2) node path + scatter, merged (independent work, one dispatch)
    mid_kernel<<<N_TILES_NODE + SCAT_BLOCKS, 256, 0, stream>>>(
        dst, count, pd, node_feats, degs, fragH, fragL, bn, res_w, h_ws, out);

    // 3) edge path: sorted-order GEMM + block-level segmented aggregation
    edge_kernel<<<N_TILES_EDGE, 256, 0, stream>>>(edge_feats, norm, src, pd,
                                                  fragE, be, h_ws, out);
}